// Round 3
// baseline (399.169 us; speedup 1.0000x reference)
//
#include <hip/hip_runtime.h>
#include <hip/hip_bf16.h>

#define B_   32
#define N_   4096
#define D_   768
#define HID_ 256

#define SX 64.0f
#define SW 1024.0f
#define INV_S (1.0f / 65536.0f)

typedef unsigned long long ull;
typedef _Float16 half8 __attribute__((ext_vector_type(8)));
typedef _Float16 half4 __attribute__((ext_vector_type(4)));
typedef float f32x16 __attribute__((ext_vector_type(16)));

// ---------------- Kernel P: split W1^T into f16 hi/lo, chunk-major ----------------
// Whi/Wlo layout: [96 chunks][256 hid][8 k] f16, chunk c covers k = c*8..c*8+7.
__global__ __launch_bounds__(256) void wsplit_kernel(
    const float* __restrict__ W1, _Float16* __restrict__ whi,
    _Float16* __restrict__ wlo) {
  int c = blockIdx.x;    // 0..95
  int h = threadIdx.x;   // 0..255
  half8 vh, vl;
#pragma unroll
  for (int j = 0; j < 8; ++j) {
    float w = W1[(size_t)(c * 8 + j) * 256 + h] * SW;
    _Float16 hi = (_Float16)w;
    vh[j] = hi;
    vl[j] = (_Float16)(w - (float)hi);
  }
  *(half8*)&whi[((size_t)c * 256 + h) * 8] = vh;
  *(half8*)&wlo[((size_t)c * 256 + h) * 8] = vl;
}

// ---------------- Kernel A: label projection + L2 normalize ----------------
__global__ __launch_bounds__(256) void proj_norm_kernel(
    const float* __restrict__ lc, const float* __restrict__ Wp,
    const float* __restrict__ bp, float* __restrict__ lbl_n) {
  int b = blockIdx.x;
  int t = threadIdx.x;
  __shared__ float s_lc[128];
  __shared__ float s_out[768];
  __shared__ float s_red[4];

  if (t < 128) s_lc[t] = lc[b * 128 + t];
  __syncthreads();

  float sumsq = 0.f;
  for (int d = t; d < D_; d += 256) {
    float acc = bp[d];
    for (int k = 0; k < 128; ++k) acc += s_lc[k] * Wp[k * D_ + d];
    s_out[d] = acc;
    sumsq += acc * acc;
  }
  for (int off = 32; off >= 1; off >>= 1) sumsq += __shfl_xor(sumsq, off);
  if ((t & 63) == 0) s_red[t >> 6] = sumsq;
  __syncthreads();
  float tot = s_red[0] + s_red[1] + s_red[2] + s_red[3];
  float inv = 1.f / fmaxf(sqrtf(tot), 1e-12f);
  for (int d = t; d < D_; d += 256) lbl_n[b * D_ + d] = s_out[d] * inv;
}

// ---------------- Kernel B: split-f16 MFMA score kernel, v3 ----------------
// Block: 4 waves = 64 patches x 256 hid. Wave (pg,hh): patches pg*32..+31,
// hidden hh*128..+127 (mt=4 tiles), acc = 4 x f32x16 = 64 VGPR.
// K16 stages (48). X loaded once per block, split to f16 hi/lo in LDS,
// shared across hidden-half waves. W staged via regs -> LDS dbuf.
__global__ __launch_bounds__(256, 3) void score3_kernel(
    const float* __restrict__ X, const _Float16* __restrict__ Whi,
    const _Float16* __restrict__ Wlo, const float* __restrict__ b1,
    const float* __restrict__ W2, const float* __restrict__ b2,
    const float* __restrict__ lbl_n, float* __restrict__ scores) {
  __shared__ __align__(16) _Float16 sW[2][2][2][256][8];  // 32KB [buf][h/l][k8][hid][8]
  __shared__ __align__(16) _Float16 sB[2][2][2][64][8];   // 8KB  [buf][h/l][k8][patch][8]
  __shared__ __align__(16) float sLbl[768];
  __shared__ float sB1[256], sW2[256];
  __shared__ float sVs[2][64];
  __shared__ float sLsc[64];

  const int t  = threadIdx.x;
  const int w  = t >> 6;
  const int l  = t & 63;
  const int l5 = l >> 5;
  const int ln = l & 31;
  const int pg = w & 1;   // patch group
  const int hh = w >> 1;  // hidden half
  const int pb = blockIdx.x * 64;
  const int batch = pb >> 12;

  for (int i = t; i < D_; i += 256) sLbl[i] = lbl_n[batch * D_ + i];
  sB1[t] = b1[t];
  sW2[t] = W2[t];

  // staging role: thread t handles patch row srow, k-quarter sk (4 floats)
  const int srow = t >> 2;
  const int sk   = t & 3;
  const float* xrow = X + (size_t)(pb + srow) * D_;

  f32x16 acc[4];
#pragma unroll
  for (int mt = 0; mt < 4; ++mt)
#pragma unroll
    for (int r = 0; r < 16; ++r) acc[mt][r] = 0.f;

  const float4* gWh = (const float4*)Whi;
  const float4* gWl = (const float4*)Wlo;

  float sq = 0.f, dt = 0.f;

  // stage-0 loads
  float4 wh0 = gWh[t],        wh1 = gWh[256 + t];
  float4 wl0 = gWl[t],        wl1 = gWl[256 + t];
  float4 xr  = *(const float4*)&xrow[sk * 4];

  __syncthreads();  // sLbl ready

  // repack stage 0 into buf 0
  {
    float4 lv = *(const float4*)&sLbl[sk * 4];
    half4 h_, l_;
#pragma unroll
    for (int j = 0; j < 4; ++j) {
      float xv = (&xr.x)[j];
      sq += xv * xv;
      dt += xv * (&lv.x)[j];
      float xs = xv * SX;
      _Float16 hi = (_Float16)xs;
      h_[j] = hi;
      l_[j] = (_Float16)(xs - (float)hi);
    }
    *(half4*)&sB[0][0][sk >> 1][srow][(sk & 1) * 4] = h_;
    *(half4*)&sB[0][1][sk >> 1][srow][(sk & 1) * 4] = l_;
    float4* dh = (float4*)&sW[0][0][0][0][0];
    float4* dl = (float4*)&sW[0][1][0][0][0];
    dh[t] = wh0; dh[256 + t] = wh1;
    dl[t] = wl0; dl[256 + t] = wl1;
  }
  __syncthreads();

  for (int s = 0; s < 48; ++s) {
    const int cur = s & 1;
    if (s < 47) {
      const int sn = s + 1;
      wh0 = gWh[sn * 512 + t];       wh1 = gWh[sn * 512 + 256 + t];
      wl0 = gWl[sn * 512 + t];       wl1 = gWl[sn * 512 + 256 + t];
      xr  = *(const float4*)&xrow[sn * 16 + sk * 4];
    }

    // compute from buf[cur]
    half8 bh = *(const half8*)&sB[cur][0][l5][pg * 32 + ln][0];
    half8 bl = *(const half8*)&sB[cur][1][l5][pg * 32 + ln][0];
#pragma unroll
    for (int mt = 0; mt < 4; ++mt) {
      half8 ah = *(const half8*)&sW[cur][0][l5][hh * 128 + mt * 32 + ln][0];
      half8 al = *(const half8*)&sW[cur][1][l5][hh * 128 + mt * 32 + ln][0];
      acc[mt] = __builtin_amdgcn_mfma_f32_32x32x16_f16(ah, bh, acc[mt], 0, 0, 0);
      acc[mt] = __builtin_amdgcn_mfma_f32_32x32x16_f16(ah, bl, acc[mt], 0, 0, 0);
      acc[mt] = __builtin_amdgcn_mfma_f32_32x32x16_f16(al, bh, acc[mt], 0, 0, 0);
    }

    if (s < 47) {
      const int nb = cur ^ 1;
      float4 lv = *(const float4*)&sLbl[(s + 1) * 16 + sk * 4];
      half4 h_, l_;
#pragma unroll
      for (int j = 0; j < 4; ++j) {
        float xv = (&xr.x)[j];
        sq += xv * xv;
        dt += xv * (&lv.x)[j];
        float xs = xv * SX;
        _Float16 hi = (_Float16)xs;
        h_[j] = hi;
        l_[j] = (_Float16)(xs - (float)hi);
      }
      *(half4*)&sB[nb][0][sk >> 1][srow][(sk & 1) * 4] = h_;
      *(half4*)&sB[nb][1][sk >> 1][srow][(sk & 1) * 4] = l_;
      float4* dh = (float4*)&sW[nb][0][0][0][0];
      float4* dl = (float4*)&sW[nb][1][0][0][0];
      dh[t] = wh0; dh[256 + t] = wh1;
      dl[t] = wl0; dl[256 + t] = wl1;
    }
    __syncthreads();
  }

  // ---- epilogue ----
  // label score per staged row
  sq += __shfl_xor(sq, 1); dt += __shfl_xor(dt, 1);
  sq += __shfl_xor(sq, 2); dt += __shfl_xor(dt, 2);
  if ((l & 3) == 0) sLsc[srow] = dt / fmaxf(sqrtf(sq), 1e-12f);

  // visual score partial (this wave's 128 hidden)
  float vs = 0.f;
#pragma unroll
  for (int mt = 0; mt < 4; ++mt) {
#pragma unroll
    for (int rq = 0; rq < 4; ++rq) {
      const int hb = hh * 128 + mt * 32 + rq * 8 + l5 * 4;
      const float4 b1v = *(const float4*)&sB1[hb];
      const float4 w2v = *(const float4*)&sW2[hb];
      float hv0 = acc[mt][rq * 4 + 0] * INV_S + b1v.x;
      float hv1 = acc[mt][rq * 4 + 1] * INV_S + b1v.y;
      float hv2 = acc[mt][rq * 4 + 2] * INV_S + b1v.z;
      float hv3 = acc[mt][rq * 4 + 3] * INV_S + b1v.w;
      vs += fmaxf(hv0, 0.f) * w2v.x;
      vs += fmaxf(hv1, 0.f) * w2v.y;
      vs += fmaxf(hv2, 0.f) * w2v.z;
      vs += fmaxf(hv3, 0.f) * w2v.w;
    }
  }
  vs += __shfl_xor(vs, 32);
  if (l < 32) sVs[hh][pg * 32 + l] = vs;
  __syncthreads();

  if (w < 2 && l < 32) {
    int p = w * 32 + l;
    float vst = sVs[0][p] + sVs[1][p] + b2[0];
    scores[pb + p] = 0.4f * vst + 0.6f * sLsc[p];
  }
}

// ---------------- Kernel C: per-batch exact top-K (descending, tie->lower idx) --
__global__ __launch_bounds__(256) void topk2_kernel(
    const float* __restrict__ scores, int* __restrict__ out_idx, int K) {
  int b = blockIdx.x;
  int t = threadIdx.x;
  __shared__ ull swm[4];

  ull keys[16];
#pragma unroll
  for (int j = 0; j < 16; ++j) {
    int i = (j << 8) + t;  // coalesced
    float s = scores[(b << 12) + i];
    unsigned u = __float_as_uint(s);
    u = (u & 0x80000000u) ? ~u : (u | 0x80000000u);
    keys[j] = ((ull)u << 32) | (unsigned)(4095 - i);  // tie -> lower index wins
  }
  ull cur = 0;
#pragma unroll
  for (int j = 0; j < 16; ++j) cur = keys[j] > cur ? keys[j] : cur;

  for (int sel = 0; sel < K; ++sel) {
    ull wb = cur;
#pragma unroll
    for (int off = 1; off < 64; off <<= 1) {
      ull o = __shfl_xor(wb, off);
      wb = o > wb ? o : wb;
    }
    if ((t & 63) == 0) swm[t >> 6] = wb;
    __syncthreads();
    ull m0 = swm[0] > swm[1] ? swm[0] : swm[1];
    ull m1 = swm[2] > swm[3] ? swm[2] : swm[3];
    ull best = m0 > m1 ? m0 : m1;
    if (t == 0) out_idx[b * K + sel] = 4095 - (int)(unsigned)(best & 0xFFFFFFFFull);
    if (cur == best) {
      cur = 0;
#pragma unroll
      for (int j = 0; j < 16; ++j)
        cur = (keys[j] < best && keys[j] > cur) ? keys[j] : cur;
    }
    __syncthreads();
  }
}

// ---------------- Kernel D: gather + float-encode indices ----------------
__global__ __launch_bounds__(192) void gather_kernel(
    const float* __restrict__ feats, const int* __restrict__ idx,
    float* __restrict__ out_feats, float* __restrict__ out_idx_f, int K) {
  int i = blockIdx.x;
  int b = blockIdx.y;
  int id = idx[b * K + i];
  const float4* src = (const float4*)&feats[((size_t)b * N_ + id) * D_];
  float4* dst = (float4*)&out_feats[((size_t)b * K + i) * D_];
  dst[threadIdx.x] = src[threadIdx.x];
  if (threadIdx.x == 0) out_idx_f[b * K + i] = (float)id;
}

extern "C" void kernel_launch(void* const* d_in, const int* in_sizes, int n_in,
                              void* d_out, int out_size, void* d_ws, size_t ws_size,
                              hipStream_t stream) {
  const float* feats = (const float*)d_in[0];
  const float* lc    = (const float*)d_in[1];
  const float* W1    = (const float*)d_in[2];
  const float* b1    = (const float*)d_in[3];
  const float* W2    = (const float*)d_in[4];
  const float* b2    = (const float*)d_in[5];
  const float* Wp    = (const float*)d_in[6];
  const float* bp    = (const float*)d_in[7];
  int K = out_size / (B_ * (D_ + 1));  // 192

  float* ws_f    = (float*)d_ws;
  float* lbl_n   = ws_f;                              // 32*768
  float* scoresv = ws_f + B_ * D_;                    // 32*4096
  int*   topidx  = (int*)(ws_f + B_ * D_ + B_ * N_);  // 32*192
  size_t off = (size_t)B_ * D_ + (size_t)B_ * N_ + B_ * 256;
  off = (off + 3) & ~(size_t)3;
  _Float16* whi = (_Float16*)(ws_f + off);            // 96*256*8 halves
  _Float16* wlo = whi + (size_t)96 * 256 * 8;

  float* out_f     = (float*)d_out;
  float* out_idx_f = out_f + (size_t)B_ * K * D_;

  wsplit_kernel<<<96, 256, 0, stream>>>(W1, whi, wlo);
  proj_norm_kernel<<<B_, 256, 0, stream>>>(lc, Wp, bp, lbl_n);
  score3_kernel<<<(B_ * N_) / 64, 256, 0, stream>>>(feats, whi, wlo, b1, W2, b2,
                                                    lbl_n, scoresv);
  topk2_kernel<<<B_, 256, 0, stream>>>(scoresv, topidx, K);
  gather_kernel<<<dim3(K, B_), 192, 0, stream>>>(feats, topidx, out_f, out_idx_f, K);
}

// Round 4
// 350.237 us; speedup vs baseline: 1.1397x; 1.1397x over previous
//
#include <hip/hip_runtime.h>
#include <hip/hip_bf16.h>

#define B_   32
#define N_   4096
#define D_   768
#define HID_ 256

#define SX 64.0f
#define SW 1024.0f
#define INV_S (1.0f / 65536.0f)

typedef unsigned long long ull;
typedef _Float16 half8 __attribute__((ext_vector_type(8)));
typedef _Float16 half4 __attribute__((ext_vector_type(4)));
typedef float f32x16 __attribute__((ext_vector_type(16)));

// ---------------- Kernel P: split W1^T into f16 hi/lo, chunk-major ----------------
// Whi/Wlo layout: [96 chunks][256 hid][8 k] f16, chunk c covers k = c*8..c*8+7.
// This IS the 32x32x16 A-fragment layout: lane ln reads 16B at (c*256+hid)*8.
__global__ __launch_bounds__(256) void wsplit_kernel(
    const float* __restrict__ W1, _Float16* __restrict__ whi,
    _Float16* __restrict__ wlo) {
  int c = blockIdx.x;    // 0..95
  int h = threadIdx.x;   // 0..255
  half8 vh, vl;
#pragma unroll
  for (int j = 0; j < 8; ++j) {
    float w = W1[(size_t)(c * 8 + j) * 256 + h] * SW;
    _Float16 hi = (_Float16)w;
    vh[j] = hi;
    vl[j] = (_Float16)(w - (float)hi);
  }
  *(half8*)&whi[((size_t)c * 256 + h) * 8] = vh;
  *(half8*)&wlo[((size_t)c * 256 + h) * 8] = vl;
}

// ---------------- Kernel A: label projection + L2 normalize ----------------
__global__ __launch_bounds__(256) void proj_norm_kernel(
    const float* __restrict__ lc, const float* __restrict__ Wp,
    const float* __restrict__ bp, float* __restrict__ lbl_n) {
  int b = blockIdx.x;
  int t = threadIdx.x;
  __shared__ float s_lc[128];
  __shared__ float s_out[768];
  __shared__ float s_red[4];

  if (t < 128) s_lc[t] = lc[b * 128 + t];
  __syncthreads();

  float sumsq = 0.f;
  for (int d = t; d < D_; d += 256) {
    float acc = bp[d];
    for (int k = 0; k < 128; ++k) acc += s_lc[k] * Wp[k * D_ + d];
    s_out[d] = acc;
    sumsq += acc * acc;
  }
  for (int off = 32; off >= 1; off >>= 1) sumsq += __shfl_xor(sumsq, off);
  if ((t & 63) == 0) s_red[t >> 6] = sumsq;
  __syncthreads();
  float tot = s_red[0] + s_red[1] + s_red[2] + s_red[3];
  float inv = 1.f / fmaxf(sqrtf(tot), 1e-12f);
  for (int d = t; d < D_; d += 256) lbl_n[b * D_ + d] = s_out[d] * inv;
}

// ---------------- Kernel B: split-f16 MFMA score kernel, v4 ----------------
// Block: 4 waves, 64 patches. Wave w owns hidden quarter [w*64, w*64+64),
// ALL 64 patches: acc[pt=2][mt=2] = 4 x f32x16 = 64 VGPR.
// W A-frags loaded DIRECTLY from global (L2-resident, pre-packed in frag order)
// with one-stage register prefetch — no LDS for W.
// X staged through small LDS dbuf (split hi/lo once per block, shared by waves).
__global__ __launch_bounds__(256, 3) void score4_kernel(
    const float* __restrict__ X, const _Float16* __restrict__ Whi,
    const _Float16* __restrict__ Wlo, const float* __restrict__ b1,
    const float* __restrict__ W2, const float* __restrict__ b2,
    const float* __restrict__ lbl_n, float* __restrict__ scores) {
  __shared__ __align__(16) _Float16 sB[2][2][2][64][8];  // [buf][h/l][k8][patch][8] = 8KB
  __shared__ __align__(16) float sLbl[768];
  __shared__ float sB1[256], sW2[256];
  __shared__ float sVs[4][64];
  __shared__ float sLsc[64];

  const int t  = threadIdx.x;
  const int w  = t >> 6;
  const int l  = t & 63;
  const int l5 = l >> 5;
  const int ln = l & 31;
  const int pb = blockIdx.x * 64;
  const int batch = pb >> 12;

  for (int i = t; i < D_; i += 256) sLbl[i] = lbl_n[batch * D_ + i];
  sB1[t] = b1[t];
  sW2[t] = W2[t];

  // staging role: thread t handles patch row srow, k-quarter sk (4 floats)
  const int srow = t >> 2;
  const int sk   = t & 3;
  const float* xrow = X + (size_t)(pb + srow) * D_;

  f32x16 acc[2][2];
#pragma unroll
  for (int pt = 0; pt < 2; ++pt)
#pragma unroll
    for (int mt = 0; mt < 2; ++mt)
#pragma unroll
      for (int r = 0; r < 16; ++r) acc[pt][mt][r] = 0.f;

  const half8* gWh = (const half8*)Whi;
  const half8* gWl = (const half8*)Wlo;
  const int hidb = w * 64 + ln;  // this lane's hidden row (mt adds +32)

  float sq = 0.f, dt = 0.f;

  // prologue: stage-0 A-frags + X
  half8 ah0 = gWh[l5 * 256 + hidb],      ah1 = gWh[l5 * 256 + hidb + 32];
  half8 al0 = gWl[l5 * 256 + hidb],      al1 = gWl[l5 * 256 + hidb + 32];
  float4 xr = *(const float4*)&xrow[sk * 4];

  __syncthreads();  // sLbl ready

  {  // split + write X stage 0 into buf 0
    float4 lv = *(const float4*)&sLbl[sk * 4];
    half4 h_, l_;
#pragma unroll
    for (int j = 0; j < 4; ++j) {
      float xv = (&xr.x)[j];
      sq += xv * xv;
      dt += xv * (&lv.x)[j];
      float xs = xv * SX;
      _Float16 hi = (_Float16)xs;
      h_[j] = hi;
      l_[j] = (_Float16)(xs - (float)hi);
    }
    *(half4*)&sB[0][0][sk >> 1][srow][(sk & 1) * 4] = h_;
    *(half4*)&sB[0][1][sk >> 1][srow][(sk & 1) * 4] = l_;
  }
  __syncthreads();

  for (int s = 0; s < 48; ++s) {
    const int cur = s & 1;
    half8 ph0, ph1, pl0, pl1;
    float4 nxr;
    if (s < 47) {
      const int c = (s + 1) * 2 + l5;
      ph0 = gWh[c * 256 + hidb];
      ph1 = gWh[c * 256 + hidb + 32];
      pl0 = gWl[c * 256 + hidb];
      pl1 = gWl[c * 256 + hidb + 32];
      nxr = *(const float4*)&xrow[(s + 1) * 16 + sk * 4];
    }

    // B-frags from LDS (shared across all 4 waves)
    half8 bh0 = *(const half8*)&sB[cur][0][l5][ln][0];
    half8 bl0 = *(const half8*)&sB[cur][1][l5][ln][0];
    half8 bh1 = *(const half8*)&sB[cur][0][l5][32 + ln][0];
    half8 bl1 = *(const half8*)&sB[cur][1][l5][32 + ln][0];

    acc[0][0] = __builtin_amdgcn_mfma_f32_32x32x16_f16(ah0, bh0, acc[0][0], 0, 0, 0);
    acc[0][1] = __builtin_amdgcn_mfma_f32_32x32x16_f16(ah1, bh0, acc[0][1], 0, 0, 0);
    acc[1][0] = __builtin_amdgcn_mfma_f32_32x32x16_f16(ah0, bh1, acc[1][0], 0, 0, 0);
    acc[1][1] = __builtin_amdgcn_mfma_f32_32x32x16_f16(ah1, bh1, acc[1][1], 0, 0, 0);
    acc[0][0] = __builtin_amdgcn_mfma_f32_32x32x16_f16(ah0, bl0, acc[0][0], 0, 0, 0);
    acc[0][1] = __builtin_amdgcn_mfma_f32_32x32x16_f16(ah1, bl0, acc[0][1], 0, 0, 0);
    acc[1][0] = __builtin_amdgcn_mfma_f32_32x32x16_f16(ah0, bl1, acc[1][0], 0, 0, 0);
    acc[1][1] = __builtin_amdgcn_mfma_f32_32x32x16_f16(ah1, bl1, acc[1][1], 0, 0, 0);
    acc[0][0] = __builtin_amdgcn_mfma_f32_32x32x16_f16(al0, bh0, acc[0][0], 0, 0, 0);
    acc[0][1] = __builtin_amdgcn_mfma_f32_32x32x16_f16(al1, bh0, acc[0][1], 0, 0, 0);
    acc[1][0] = __builtin_amdgcn_mfma_f32_32x32x16_f16(al0, bh1, acc[1][0], 0, 0, 0);
    acc[1][1] = __builtin_amdgcn_mfma_f32_32x32x16_f16(al1, bh1, acc[1][1], 0, 0, 0);

    if (s < 47) {
      const int nb = cur ^ 1;
      float4 lv = *(const float4*)&sLbl[(s + 1) * 16 + sk * 4];
      half4 h_, l_;
#pragma unroll
      for (int j = 0; j < 4; ++j) {
        float xv = (&nxr.x)[j];
        sq += xv * xv;
        dt += xv * (&lv.x)[j];
        float xs = xv * SX;
        _Float16 hi = (_Float16)xs;
        h_[j] = hi;
        l_[j] = (_Float16)(xs - (float)hi);
      }
      *(half4*)&sB[nb][0][sk >> 1][srow][(sk & 1) * 4] = h_;
      *(half4*)&sB[nb][1][sk >> 1][srow][(sk & 1) * 4] = l_;
      ah0 = ph0; ah1 = ph1; al0 = pl0; al1 = pl1;
    }
    __syncthreads();
  }

  // ---- epilogue ----
  // label score per staged row (4 threads per row: sk lanes)
  sq += __shfl_xor(sq, 1); dt += __shfl_xor(dt, 1);
  sq += __shfl_xor(sq, 2); dt += __shfl_xor(dt, 2);
  if ((l & 3) == 0) sLsc[srow] = dt / fmaxf(sqrtf(sq), 1e-12f);

  // visual score partial (this wave's 64 hidden, both patch tiles)
  float vs0 = 0.f, vs1 = 0.f;
#pragma unroll
  for (int mt = 0; mt < 2; ++mt) {
#pragma unroll
    for (int rq = 0; rq < 4; ++rq) {
      const int hb = w * 64 + mt * 32 + rq * 8 + l5 * 4;
      const float4 b1v = *(const float4*)&sB1[hb];
      const float4 w2v = *(const float4*)&sW2[hb];
#pragma unroll
      for (int j = 0; j < 4; ++j) {
        float h0 = acc[0][mt][rq * 4 + j] * INV_S + (&b1v.x)[j];
        float h1 = acc[1][mt][rq * 4 + j] * INV_S + (&b1v.x)[j];
        vs0 += fmaxf(h0, 0.f) * (&w2v.x)[j];
        vs1 += fmaxf(h1, 0.f) * (&w2v.x)[j];
      }
    }
  }
  vs0 += __shfl_xor(vs0, 32);
  vs1 += __shfl_xor(vs1, 32);
  if (l < 32) {
    sVs[w][l]      = vs0;
    sVs[w][32 + l] = vs1;
  }
  __syncthreads();

  if (t < 64) {
    float vst = sVs[0][t] + sVs[1][t] + sVs[2][t] + sVs[3][t] + b2[0];
    scores[pb + t] = 0.4f * vst + 0.6f * sLsc[t];
  }
}

// ---------------- Kernel C: per-batch exact top-K (descending, tie->lower idx) --
__global__ __launch_bounds__(256) void topk2_kernel(
    const float* __restrict__ scores, int* __restrict__ out_idx, int K) {
  int b = blockIdx.x;
  int t = threadIdx.x;
  __shared__ ull swm[4];

  ull keys[16];
#pragma unroll
  for (int j = 0; j < 16; ++j) {
    int i = (j << 8) + t;  // coalesced
    float s = scores[(b << 12) + i];
    unsigned u = __float_as_uint(s);
    u = (u & 0x80000000u) ? ~u : (u | 0x80000000u);
    keys[j] = ((ull)u << 32) | (unsigned)(4095 - i);  // tie -> lower index wins
  }
  ull cur = 0;
#pragma unroll
  for (int j = 0; j < 16; ++j) cur = keys[j] > cur ? keys[j] : cur;

  for (int sel = 0; sel < K; ++sel) {
    ull wb = cur;
#pragma unroll
    for (int off = 1; off < 64; off <<= 1) {
      ull o = __shfl_xor(wb, off);
      wb = o > wb ? o : wb;
    }
    if ((t & 63) == 0) swm[t >> 6] = wb;
    __syncthreads();
    ull m0 = swm[0] > swm[1] ? swm[0] : swm[1];
    ull m1 = swm[2] > swm[3] ? swm[2] : swm[3];
    ull best = m0 > m1 ? m0 : m1;
    if (t == 0) out_idx[b * K + sel] = 4095 - (int)(unsigned)(best & 0xFFFFFFFFull);
    if (cur == best) {
      cur = 0;
#pragma unroll
      for (int j = 0; j < 16; ++j)
        cur = (keys[j] < best && keys[j] > cur) ? keys[j] : cur;
    }
    __syncthreads();
  }
}

// ---------------- Kernel D: gather + float-encode indices ----------------
__global__ __launch_bounds__(192) void gather_kernel(
    const float* __restrict__ feats, const int* __restrict__ idx,
    float* __restrict__ out_feats, float* __restrict__ out_idx_f, int K) {
  int i = blockIdx.x;
  int b = blockIdx.y;
  int id = idx[b * K + i];
  const float4* src = (const float4*)&feats[((size_t)b * N_ + id) * D_];
  float4* dst = (float4*)&out_feats[((size_t)b * K + i) * D_];
  dst[threadIdx.x] = src[threadIdx.x];
  if (threadIdx.x == 0) out_idx_f[b * K + i] = (float)id;
}

extern "C" void kernel_launch(void* const* d_in, const int* in_sizes, int n_in,
                              void* d_out, int out_size, void* d_ws, size_t ws_size,
                              hipStream_t stream) {
  const float* feats = (const float*)d_in[0];
  const float* lc    = (const float*)d_in[1];
  const float* W1    = (const float*)d_in[2];
  const float* b1    = (const float*)d_in[3];
  const float* W2    = (const float*)d_in[4];
  const float* b2    = (const float*)d_in[5];
  const float* Wp    = (const float*)d_in[6];
  const float* bp    = (const float*)d_in[7];
  int K = out_size / (B_ * (D_ + 1));  // 192

  float* ws_f    = (float*)d_ws;
  float* lbl_n   = ws_f;                              // 32*768
  float* scoresv = ws_f + B_ * D_;                    // 32*4096
  int*   topidx  = (int*)(ws_f + B_ * D_ + B_ * N_);  // 32*192
  size_t off = (size_t)B_ * D_ + (size_t)B_ * N_ + B_ * 256;
  off = (off + 3) & ~(size_t)3;
  _Float16* whi = (_Float16*)(ws_f + off);            // 96*256*8 halves
  _Float16* wlo = whi + (size_t)96 * 256 * 8;

  float* out_f     = (float*)d_out;
  float* out_idx_f = out_f + (size_t)B_ * K * D_;

  wsplit_kernel<<<96, 256, 0, stream>>>(W1, whi, wlo);
  proj_norm_kernel<<<B_, 256, 0, stream>>>(lc, Wp, bp, lbl_n);
  score4_kernel<<<(B_ * N_) / 64, 256, 0, stream>>>(feats, whi, wlo, b1, W2, b2,
                                                    lbl_n, scoresv);
  topk2_kernel<<<B_, 256, 0, stream>>>(scoresv, topidx, K);
  gather_kernel<<<dim3(K, B_), 192, 0, stream>>>(feats, topidx, out_f, out_idx_f, K);
}